// Round 10
// baseline (1140.821 us; speedup 1.0000x reference)
//
#include <hip/hip_runtime.h>

#define B_     4
#define T_     4096
#define C_     1024
#define H_     4096
#define BT_    (B_ * T_)
#define NCH_   64
#define CHLEN_ 64
#define MCHUNK 8192   // rows per h-chunk for GEMM2a/2b (2 chunks)

typedef __bf16 bf16_t;
typedef __bf16 bf16x8 __attribute__((ext_vector_type(8)));
typedef float  f32x4  __attribute__((ext_vector_type(4)));

__device__ __forceinline__ float hs_f(float v) {
    return fminf(fmaxf((v + 3.0f) * (1.0f / 6.0f), 0.0f), 1.0f) - 0.5f;
}

__device__ __forceinline__ void gld_lds16(const bf16_t* g, bf16_t* l) {
    __builtin_amdgcn_global_load_lds((const __attribute__((address_space(1))) void*)g,
                                     (__attribute__((address_space(3))) void*)l,
                                     16, 0, 0);
}

// ---------------------------------------------------------------------------
__global__ __launch_bounds__(256) void rms_rows_f32(const float* __restrict__ X,
                                                    float* __restrict__ inv) {
    const int wave = threadIdx.x >> 6, lane = threadIdx.x & 63;
    const int row = blockIdx.x * 4 + wave;
    const float* xr = X + (size_t)row * C_;
    float s = 0.0f;
    #pragma unroll
    for (int p = 0; p < 4; p++) {
        float4 v = *(const float4*)(xr + p * 256 + lane * 4);
        s += v.x * v.x + v.y * v.y + v.z * v.z + v.w * v.w;
    }
    #pragma unroll
    for (int o = 32; o > 0; o >>= 1) s += __shfl_down(s, o, 64);
    if (lane == 0) inv[row] = rsqrtf(s * (1.0f / C_) + 1e-6f);
}

// ---------------------------------------------------------------------------
__global__ __launch_bounds__(256) void scan_emit_local(const float* __restrict__ X,
                                                       const float* __restrict__ inv1,
                                                       const float* __restrict__ nw,
                                                       bf16_t* __restrict__ state,
                                                       float* __restrict__ csum) {
    const int bch = blockIdx.x;
    const int b = bch >> 6, ch = bch & 63;
    const int c = blockIdx.y * 256 + threadIdx.x;
    const float wgt = nw[c];
    const int rbase = b * T_ + ch * CHLEN_;
    const size_t xbase = (size_t)rbase * C_ + c;
    float acc = 0.0f;
    for (int i = 0; i < CHLEN_; i++) {
        acc += hs_f(X[xbase + (size_t)i * C_] * inv1[rbase + i] * wgt);
        state[(size_t)(rbase + i) * C_ + c] = (bf16_t)acc;
    }
    csum[(size_t)bch * C_ + c] = acc;
}

__global__ __launch_bounds__(256) void scan_offsets_hilo(const float* __restrict__ csum,
                                                         bf16_t* __restrict__ hilo) {
    const int idx = blockIdx.x * 256 + threadIdx.x;   // b*1024 + c
    const int b = idx >> 10, c = idx & 1023;
    const size_t base = (size_t)b * NCH_ * C_ + c;
    float v[NCH_];
    #pragma unroll
    for (int ch = 0; ch < NCH_; ch++)
        v[ch] = csum[base + (size_t)ch * C_];
    float run = 0.0f;
    #pragma unroll
    for (int ch = 0; ch < NCH_; ch++) {
        const size_t row = (size_t)(b * NCH_ + ch) * 2048 + c;
        const bf16_t hi = (bf16_t)run;
        hilo[row] = hi;
        hilo[row + 1024] = (bf16_t)(run - (float)hi);
        run += v[ch];
    }
}

// Pmat = b1 broadcast (split-K P-GEMM seeds on top); also zero rs2 (GEMM1's
// fused sum-of-squares accumulator).
__global__ __launch_bounds__(256) void pmat_init(const float* __restrict__ b1,
                                                 float* __restrict__ Pmat,
                                                 float* __restrict__ rs2) {
    const int i = blockIdx.x * 256 + threadIdx.x;
    Pmat[i] = b1[i & (C_ - 1)];
    if (i < BT_) rs2[i] = 0.0f;
}

// inv2 = rsqrt(rs2/C + eps) — finish for the fused GEMM1 row sum-of-squares.
__global__ __launch_bounds__(256) void inv_finish(const float* __restrict__ rs2,
                                                  float* __restrict__ inv) {
    const int i = blockIdx.x * 256 + threadIdx.x;
    inv[i] = rsqrtf(rs2[i] * (1.0f / C_) + 1e-6f);
}

// ---------------------------------------------------------------------------
// All 3 weight transposes in ONE launch (R10: fewer serialized launch gaps).
// flat block id decodes job: [0,1024) w1->W1cat (dup halves), [1024,5120)
// w2a->W2at (n2w folded), [5120,9216) w2b->W2bt. Inner body identical to the
// R8 transpose_scale.
// ---------------------------------------------------------------------------
__global__ __launch_bounds__(256) void transpose_all(const float* __restrict__ w1,
                                                     const float* __restrict__ w2a,
                                                     const float* __restrict__ w2b,
                                                     const float* __restrict__ n2w,
                                                     bf16_t* __restrict__ W1cat,
                                                     bf16_t* __restrict__ W2at,
                                                     bf16_t* __restrict__ W2bt) {
    __shared__ float tile[32][33];
    const int flat = blockIdx.x;
    const float* src; bf16_t* dst; const float* scale;
    int N, ldd, dupOff, bx, by;
    if (flat < 1024) {          // w1 -> W1cat: K=C,N=C, ldd=2048, dup
        src = w1; dst = W1cat; scale = nullptr;
        N = C_; ldd = 2048; dupOff = 1024;
        bx = flat & 31; by = flat >> 5;               // 32 x 32
    } else if (flat < 5120) {   // w2a -> W2at: K=C,N=H, ldd=C, scale=n2w
        const int f = flat - 1024;
        src = w2a; dst = W2at; scale = n2w;
        N = H_; ldd = C_; dupOff = 0;
        bx = f & 127; by = f >> 7;                    // 128 x 32
    } else {                    // w2b -> W2bt: K=H,N=C, ldd=H
        const int f = flat - 5120;
        src = w2b; dst = W2bt; scale = nullptr;
        N = C_; ldd = H_; dupOff = 0;
        bx = f & 31; by = f >> 5;                     // 32 x 128
    }
    const int n0 = bx * 32, k0 = by * 32;
    const int tx = threadIdx.x & 31, ty = threadIdx.x >> 5;
    #pragma unroll
    for (int j = 0; j < 4; j++) {
        const int kk = ty + j * 8;
        float v = src[(size_t)(k0 + kk) * N + n0 + tx];
        if (scale) v *= scale[k0 + kk];
        tile[kk][tx] = v;
    }
    __syncthreads();
    #pragma unroll
    for (int j = 0; j < 4; j++) {
        const int nn = ty + j * 8;
        const bf16_t v = (bf16_t)tile[tx][nn];
        dst[(size_t)(n0 + nn) * ldd + k0 + tx] = v;
        if (dupOff) dst[(size_t)(n0 + nn) * ldd + dupOff + k0 + tx] = v;
    }
}

// ---------------------------------------------------------------------------
// 128x128 GEMM, 2-deep pipelined (R8-verified structure, unchanged):
//   prologue: STAGE(buf0,k0); STAGE(buf1,k0+32)
//   iter t:   vmcnt(4|0) -> s_barrier -> ds_read+MFMA(buf t&1) -> s_barrier
//             -> STAGE(buf t&1, k+64)
// Counted vmcnt (T4): never drained to 0 mid-loop. Swizzle (T2, R6-verified
// bank-conflict 8.4M -> 0): phys slot s' = s ^ ((row>>1)&3), LDS dest linear,
// global source pre-swizzled, ds_read same XOR (rule #21).
//
// R10: MINW template param -> __launch_bounds__(256, MINW). R8 PMC showed
// VGPR=108 caps at 4 waves/SIMD (16/CU) while LDS (32KB) allows 5 blocks.
// MINW=5 caps VGPR at 102 -> 5 blocks/CU (+25% waves) for MODE 1/2.
// MODE 0 keeps MINW=4 (fused rms needs +16 VGPR for sq[4][4]).
//
// MODE 0: out bf16 = hs(acc + pmat[(m>>6)*N+n]) * xf32[m*N+n]; also
//         accumulates row sum-of-squares of the bf16-rounded output into
//         aux[m] via shfl-reduce + atomicAdd (replaces rms_rows_bf16 pass).
// MODE 1: out bf16 = relu(rowscale[m]*acc + bias[n])            (GEMM2a)
// MODE 2: out f32  = acc + bias[n] + (f32)extra_bf16[m*N+n]     (GEMM2b)
// MODE 4: atomicAdd(out f32, acc)                               (split-K P-GEMM)
// ---------------------------------------------------------------------------
template <int MODE, int MINW, typename ET, typename OT>
__global__ __launch_bounds__(256, MINW) void gemm_bt(const bf16_t* __restrict__ A,
                                                     const bf16_t* __restrict__ Bt,
                                                     const float* __restrict__ bias,
                                                     const ET* __restrict__ extra,
                                                     const float* __restrict__ rowscale,
                                                     const float* __restrict__ pmat,
                                                     float* __restrict__ aux,
                                                     OT* __restrict__ Cmat,
                                                     int N, int K, int lda, int ldb) {
    __shared__ __align__(16) bf16_t As[2][128 * 32];
    __shared__ __align__(16) bf16_t Bs[2][128 * 32];
    const int tid = threadIdx.x;

    const int nwgx = gridDim.x;
    const int flat0 = blockIdx.y * nwgx + blockIdx.x;
    int mTile, nTile;
    if ((nwgx & 7) == 0) {                  // XCD m-slice mapping (R3 win)
        const int xcd = flat0 & 7;
        const int loc = flat0 >> 3;
        const int mpx = nwgx >> 3;
        mTile = xcd * mpx + (loc % mpx);
        nTile = loc / mpx;
    } else {
        mTile = blockIdx.x;
        nTile = blockIdx.y;
    }
    const int mBase = mTile * 128;
    const int nBase = nTile * 128;
    const size_t kOff = (size_t)blockIdx.z * K;

    const int wave = tid >> 6;
    const int lane = tid & 63;
    const int waveM = (wave & 1) * 64;
    const int waveN = (wave >> 1) * 64;
    const int lr = lane & 15;
    const int lq = lane >> 4;

    f32x4 acc[4][4] = {};

    const int e0 = tid * 8;
    const int r0 = e0 >> 5, c0 = (((e0 >> 3) & 3) ^ ((r0 >> 1) & 3)) << 3;
    const int e1 = 2048 + tid * 8;
    const int r1 = e1 >> 5, c1 = (((e1 >> 3) & 3) ^ ((r1 >> 1) & 3)) << 3;

    const bf16_t* Ag0 = A + (size_t)(mBase + r0) * lda + kOff + c0;
    const bf16_t* Ag1 = A + (size_t)(mBase + r1) * lda + kOff + c1;
    const bf16_t* Bg0 = Bt + (size_t)(nBase + r0) * ldb + kOff + c0;
    const bf16_t* Bg1 = Bt + (size_t)(nBase + r1) * ldb + kOff + c1;

    auto stage = [&](int buf, int kb) {
        gld_lds16(Ag0 + kb, As[buf] + e0);
        gld_lds16(Ag1 + kb, As[buf] + e1);
        gld_lds16(Bg0 + kb, Bs[buf] + e0);
        gld_lds16(Bg1 + kb, Bs[buf] + e1);
    };

    stage(0, 0);
    if (32 < K) stage(1, 32);

    int cur = 0;
    for (int kb = 0; kb < K; kb += 32) {
        if (kb + 32 < K) asm volatile("s_waitcnt vmcnt(4)" ::: "memory");
        else             asm volatile("s_waitcnt vmcnt(0)" ::: "memory");
        __builtin_amdgcn_s_barrier();       // buf cur staged for all waves

        bf16x8 af[4], bfr[4];
        #pragma unroll
        for (int mi = 0; mi < 4; mi++) {
            const int R = waveM + mi * 16 + lr;
            af[mi] = *(const bf16x8*)(As[cur] + R * 32 + ((lq ^ ((R >> 1) & 3)) << 3));
        }
        #pragma unroll
        for (int ni = 0; ni < 4; ni++) {
            const int R = waveN + ni * 16 + lr;
            bfr[ni] = *(const bf16x8*)(Bs[cur] + R * 32 + ((lq ^ ((R >> 1) & 3)) << 3));
        }
        #pragma unroll
        for (int mi = 0; mi < 4; mi++)
            #pragma unroll
            for (int ni = 0; ni < 4; ni++)
                acc[mi][ni] = __builtin_amdgcn_mfma_f32_16x16x32_bf16(
                    af[mi], bfr[ni], acc[mi][ni], 0, 0, 0);

        __builtin_amdgcn_s_barrier();       // all waves done reading buf cur
        if (kb + 64 < K) stage(cur, kb + 64);
        cur ^= 1;
    }

    // Epilogue. C/D layout: col(n)=lane&15, row(m)=(lane>>4)*4+reg.
    float sq[4][4];                          // MODE 0 only: per-(mi,r) sum v^2
    if (MODE == 0) {
        #pragma unroll
        for (int a = 0; a < 4; a++)
            #pragma unroll
            for (int b = 0; b < 4; b++) sq[a][b] = 0.0f;
    }
    #pragma unroll
    for (int ni = 0; ni < 4; ni++) {
        const int n = nBase + waveN + ni * 16 + lr;
        const float bz = (MODE == 1 || MODE == 2) ? bias[n] : 0.0f;
        #pragma unroll
        for (int mi = 0; mi < 4; mi++) {
            #pragma unroll
            for (int r = 0; r < 4; r++) {
                const int m = mBase + waveM + mi * 16 + lq * 4 + r;
                float v = acc[mi][ni][r];
                if (MODE == 0) {
                    v = hs_f(v + pmat[(size_t)(m >> 6) * N + n]) * (float)extra[(size_t)m * N + n];
                    const OT vs = (OT)v;
                    Cmat[(size_t)m * N + n] = vs;
                    const float vb = (float)vs;      // bf16-rounded, matches old pass
                    sq[mi][r] += vb * vb;
                } else if (MODE == 1) {
                    v = fmaxf(rowscale[m] * v + bz, 0.0f);
                    Cmat[(size_t)m * N + n] = (OT)v;
                } else if (MODE == 2) {
                    v = v + bz + (float)extra[(size_t)m * N + n];
                    Cmat[(size_t)m * N + n] = (OT)v;
                } else {
                    atomicAdd((float*)&Cmat[(size_t)m * N + n], v);
                }
            }
        }
    }
    if (MODE == 0) {
        // Reduce over the 16-lane column group (lr); lanes lr==0 own the row.
        #pragma unroll
        for (int mi = 0; mi < 4; mi++) {
            #pragma unroll
            for (int r = 0; r < 4; r++) {
                float s = sq[mi][r];
                s += __shfl_xor(s, 1, 64);
                s += __shfl_xor(s, 2, 64);
                s += __shfl_xor(s, 4, 64);
                s += __shfl_xor(s, 8, 64);
                if (lr == 0) {
                    const int m = mBase + waveM + mi * 16 + lq * 4 + r;
                    atomicAdd(&aux[m], s);
                }
            }
        }
    }
}

// ---------------------------------------------------------------------------
extern "C" void kernel_launch(void* const* d_in, const int* in_sizes, int n_in,
                              void* d_out, int out_size, void* d_ws, size_t ws_size,
                              hipStream_t stream) {
    const float* x   = (const float*)d_in[0];
    const float* n1w = (const float*)d_in[1];
    const float* w1  = (const float*)d_in[2];
    const float* b1  = (const float*)d_in[3];
    const float* n2w = (const float*)d_in[4];
    const float* w2a = (const float*)d_in[5];
    const float* b2a = (const float*)d_in[6];
    const float* w2b = (const float*)d_in[7];
    const float* b2b = (const float*)d_in[8];
    float* y = (float*)d_out;

    char* w = (char*)d_ws;
    float*  inv1  = (float*)(w + 0);
    float*  inv2  = (float*)(w + 65536);
    float*  csum  = (float*)(w + 131072);    // also rs2 after scan (64KB head)
    bf16_t* hilo  = (bf16_t*)(w + 1179648);
    float*  Pmat  = (float*)(w + 2228224);
    bf16_t* W1cat = (bf16_t*)(w + 5373952);
    bf16_t* W2at  = (bf16_t*)(w + 9568256);
    bf16_t* W2bt  = (bf16_t*)(w + 17956864);
    bf16_t* outb  = (bf16_t*)(w + 26345472);
    bf16_t* state = (bf16_t*)(w + 59899904);
    bf16_t* hbuf  = state;
    float*  rs2   = csum;                    // csum dead after scan_offsets_hilo

    rms_rows_f32<<<dim3(BT_ / 4), dim3(256), 0, stream>>>(x, inv1);
    scan_emit_local<<<dim3(B_ * NCH_, C_ / 256), dim3(256), 0, stream>>>(x, inv1, n1w, state, csum);
    scan_offsets_hilo<<<dim3(B_ * C_ / 256), dim3(256), 0, stream>>>(csum, hilo);
    transpose_all<<<dim3(9216), dim3(256), 0, stream>>>(
        w1, w2a, w2b, n2w, W1cat, W2at, W2bt);
    pmat_init<<<dim3(256 * C_ / 256), dim3(256), 0, stream>>>(b1, Pmat, rs2);
    gemm_bt<4, 4, float, float><<<dim3(2, C_ / 128, 4), dim3(256), 0, stream>>>(
        hilo, W1cat, nullptr, nullptr, nullptr, nullptr, nullptr, Pmat, C_, 512, 2048, 2048);
    // GEMM1: M=16384, N=1024, K=1024 -> 128x8 = 1024 blocks (+fused rms sumsq)
    gemm_bt<0, 4, float, bf16_t><<<dim3(BT_ / 128, C_ / 128), dim3(256), 0, stream>>>(
        state, W1cat, nullptr, x, nullptr, Pmat, rs2, outb, C_, C_, C_, 2048);
    inv_finish<<<dim3(BT_ / 256), dim3(256), 0, stream>>>(rs2, inv2);
    for (int c = 0; c < BT_ / MCHUNK; c++) {
        const bf16_t* Ao = outb + (size_t)c * MCHUNK * C_;
        float* yo = y + (size_t)c * MCHUNK * C_;
        // GEMM2a: M=8192, N=4096, K=1024 -> 64x32 = 2048 blocks, MINW=5
        gemm_bt<1, 5, float, bf16_t><<<dim3(MCHUNK / 128, H_ / 128), dim3(256), 0, stream>>>(
            Ao, W2at, b2a, nullptr, inv2 + c * MCHUNK, nullptr, nullptr, hbuf, H_, C_, C_, C_);
        // GEMM2b: M=8192, N=1024, K=4096 -> 64x8 = 512 blocks, MINW=5
        gemm_bt<2, 5, bf16_t, float><<<dim3(MCHUNK / 128, C_ / 128), dim3(256), 0, stream>>>(
            hbuf, W2bt, b2b, Ao, nullptr, nullptr, nullptr, yo, C_, H_, H_, H_);
    }
}

// Round 11
// 605.748 us; speedup vs baseline: 1.8833x; 1.8833x over previous
//
#include <hip/hip_runtime.h>

#define B_     4
#define T_     4096
#define C_     1024
#define H_     4096
#define BT_    (B_ * T_)
#define NCH_   64
#define CHLEN_ 64
#define MCHUNK 8192   // rows per h-chunk for GEMM2a/2b (2 chunks)

typedef __bf16 bf16_t;
typedef __bf16 bf16x8 __attribute__((ext_vector_type(8)));
typedef float  f32x4  __attribute__((ext_vector_type(4)));

__device__ __forceinline__ float hs_f(float v) {
    return fminf(fmaxf((v + 3.0f) * (1.0f / 6.0f), 0.0f), 1.0f) - 0.5f;
}

__device__ __forceinline__ void gld_lds16(const bf16_t* g, bf16_t* l) {
    __builtin_amdgcn_global_load_lds((const __attribute__((address_space(1))) void*)g,
                                     (__attribute__((address_space(3))) void*)l,
                                     16, 0, 0);
}

// ---------------------------------------------------------------------------
__global__ __launch_bounds__(256) void rms_rows_f32(const float* __restrict__ X,
                                                    float* __restrict__ inv) {
    const int wave = threadIdx.x >> 6, lane = threadIdx.x & 63;
    const int row = blockIdx.x * 4 + wave;
    const float* xr = X + (size_t)row * C_;
    float s = 0.0f;
    #pragma unroll
    for (int p = 0; p < 4; p++) {
        float4 v = *(const float4*)(xr + p * 256 + lane * 4);
        s += v.x * v.x + v.y * v.y + v.z * v.z + v.w * v.w;
    }
    #pragma unroll
    for (int o = 32; o > 0; o >>= 1) s += __shfl_down(s, o, 64);
    if (lane == 0) inv[row] = rsqrtf(s * (1.0f / C_) + 1e-6f);
}

// ---------------------------------------------------------------------------
__global__ __launch_bounds__(256) void scan_emit_local(const float* __restrict__ X,
                                                       const float* __restrict__ inv1,
                                                       const float* __restrict__ nw,
                                                       bf16_t* __restrict__ state,
                                                       float* __restrict__ csum) {
    const int bch = blockIdx.x;
    const int b = bch >> 6, ch = bch & 63;
    const int c = blockIdx.y * 256 + threadIdx.x;
    const float wgt = nw[c];
    const int rbase = b * T_ + ch * CHLEN_;
    const size_t xbase = (size_t)rbase * C_ + c;
    float acc = 0.0f;
    for (int i = 0; i < CHLEN_; i++) {
        acc += hs_f(X[xbase + (size_t)i * C_] * inv1[rbase + i] * wgt);
        state[(size_t)(rbase + i) * C_ + c] = (bf16_t)acc;
    }
    csum[(size_t)bch * C_ + c] = acc;
}

__global__ __launch_bounds__(256) void scan_offsets_hilo(const float* __restrict__ csum,
                                                         bf16_t* __restrict__ hilo) {
    const int idx = blockIdx.x * 256 + threadIdx.x;   // b*1024 + c
    const int b = idx >> 10, c = idx & 1023;
    const size_t base = (size_t)b * NCH_ * C_ + c;
    float v[NCH_];
    #pragma unroll
    for (int ch = 0; ch < NCH_; ch++)
        v[ch] = csum[base + (size_t)ch * C_];
    float run = 0.0f;
    #pragma unroll
    for (int ch = 0; ch < NCH_; ch++) {
        const size_t row = (size_t)(b * NCH_ + ch) * 2048 + c;
        const bf16_t hi = (bf16_t)run;
        hilo[row] = hi;
        hilo[row + 1024] = (bf16_t)(run - (float)hi);
        run += v[ch];
    }
}

// Pmat = b1 broadcast (split-K P-GEMM seeds on top); also zero rs2 (GEMM1's
// fused sum-of-squares accumulator).
__global__ __launch_bounds__(256) void pmat_init(const float* __restrict__ b1,
                                                 float* __restrict__ Pmat,
                                                 float* __restrict__ rs2) {
    const int i = blockIdx.x * 256 + threadIdx.x;
    Pmat[i] = b1[i & (C_ - 1)];
    if (i < BT_) rs2[i] = 0.0f;
}

// inv2 = rsqrt(rs2/C + eps) — finish for the fused GEMM1 row sum-of-squares.
__global__ __launch_bounds__(256) void inv_finish(const float* __restrict__ rs2,
                                                  float* __restrict__ inv) {
    const int i = blockIdx.x * 256 + threadIdx.x;
    inv[i] = rsqrtf(rs2[i] * (1.0f / C_) + 1e-6f);
}

// ---------------------------------------------------------------------------
// All 3 weight transposes in ONE launch (R10 merge, kept — fewer launch gaps).
// ---------------------------------------------------------------------------
__global__ __launch_bounds__(256) void transpose_all(const float* __restrict__ w1,
                                                     const float* __restrict__ w2a,
                                                     const float* __restrict__ w2b,
                                                     const float* __restrict__ n2w,
                                                     bf16_t* __restrict__ W1cat,
                                                     bf16_t* __restrict__ W2at,
                                                     bf16_t* __restrict__ W2bt) {
    __shared__ float tile[32][33];
    const int flat = blockIdx.x;
    const float* src; bf16_t* dst; const float* scale;
    int N, ldd, dupOff, bx, by;
    if (flat < 1024) {          // w1 -> W1cat: K=C,N=C, ldd=2048, dup
        src = w1; dst = W1cat; scale = nullptr;
        N = C_; ldd = 2048; dupOff = 1024;
        bx = flat & 31; by = flat >> 5;               // 32 x 32
    } else if (flat < 5120) {   // w2a -> W2at: K=C,N=H, ldd=C, scale=n2w
        const int f = flat - 1024;
        src = w2a; dst = W2at; scale = n2w;
        N = H_; ldd = C_; dupOff = 0;
        bx = f & 127; by = f >> 7;                    // 128 x 32
    } else {                    // w2b -> W2bt: K=H,N=C, ldd=H
        const int f = flat - 5120;
        src = w2b; dst = W2bt; scale = nullptr;
        N = C_; ldd = H_; dupOff = 0;
        bx = f & 31; by = f >> 5;                     // 32 x 128
    }
    const int n0 = bx * 32, k0 = by * 32;
    const int tx = threadIdx.x & 31, ty = threadIdx.x >> 5;
    #pragma unroll
    for (int j = 0; j < 4; j++) {
        const int kk = ty + j * 8;
        float v = src[(size_t)(k0 + kk) * N + n0 + tx];
        if (scale) v *= scale[k0 + kk];
        tile[kk][tx] = v;
    }
    __syncthreads();
    #pragma unroll
    for (int j = 0; j < 4; j++) {
        const int nn = ty + j * 8;
        const bf16_t v = (bf16_t)tile[tx][nn];
        dst[(size_t)(n0 + nn) * ldd + k0 + tx] = v;
        if (dupOff) dst[(size_t)(n0 + nn) * ldd + dupOff + k0 + tx] = v;
    }
}

// ---------------------------------------------------------------------------
// 128x128 GEMM, 2-deep pipelined (R8-verified, 607us config: VGPR=108,
// 4 waves/SIMD, NO min-waves bound).
// R10 LESSON (PMC): __launch_bounds__(256,5) forced the allocator from 108
// to 48 VGPR -> accumulator spill to scratch (WRITE_SIZE 65->388 MB, 2.3x
// slower). Min-waves is NOT a safe occupancy lever when the kernel needs
// ~108 VGPR. Plain (256) restored.
//
//   prologue: STAGE(buf0,k0); STAGE(buf1,k0+32)
//   iter t:   vmcnt(4|0) -> s_barrier -> ds_read+MFMA(buf t&1) -> s_barrier
//             -> STAGE(buf t&1, k+64)
// Counted vmcnt (T4): never drained to 0 mid-loop. Swizzle (T2, R6-verified
// bank-conflict 8.4M -> 0): phys slot s' = s ^ ((row>>1)&3), LDS dest linear,
// global source pre-swizzled, ds_read same XOR (rule #21).
//
// MODE 0: out bf16 = hs(acc + pmat[(m>>6)*N+n]) * xf32[m*N+n]; also
//         accumulates row sum-of-squares of the bf16-rounded output into
//         aux[m] via shfl-reduce + atomicAdd (replaces rms_rows_bf16 pass).
// MODE 1: out bf16 = relu(rowscale[m]*acc + bias[n])            (GEMM2a)
// MODE 2: out f32  = acc + bias[n] + (f32)extra_bf16[m*N+n]     (GEMM2b)
// MODE 4: atomicAdd(out f32, acc)                               (split-K P-GEMM)
// ---------------------------------------------------------------------------
template <int MODE, typename ET, typename OT>
__global__ __launch_bounds__(256) void gemm_bt(const bf16_t* __restrict__ A,
                                               const bf16_t* __restrict__ Bt,
                                               const float* __restrict__ bias,
                                               const ET* __restrict__ extra,
                                               const float* __restrict__ rowscale,
                                               const float* __restrict__ pmat,
                                               float* __restrict__ aux,
                                               OT* __restrict__ Cmat,
                                               int N, int K, int lda, int ldb) {
    __shared__ __align__(16) bf16_t As[2][128 * 32];
    __shared__ __align__(16) bf16_t Bs[2][128 * 32];
    const int tid = threadIdx.x;

    const int nwgx = gridDim.x;
    const int flat0 = blockIdx.y * nwgx + blockIdx.x;
    int mTile, nTile;
    if ((nwgx & 7) == 0) {                  // XCD m-slice mapping (R3 win)
        const int xcd = flat0 & 7;
        const int loc = flat0 >> 3;
        const int mpx = nwgx >> 3;
        mTile = xcd * mpx + (loc % mpx);
        nTile = loc / mpx;
    } else {
        mTile = blockIdx.x;
        nTile = blockIdx.y;
    }
    const int mBase = mTile * 128;
    const int nBase = nTile * 128;
    const size_t kOff = (size_t)blockIdx.z * K;

    const int wave = tid >> 6;
    const int lane = tid & 63;
    const int waveM = (wave & 1) * 64;
    const int waveN = (wave >> 1) * 64;
    const int lr = lane & 15;
    const int lq = lane >> 4;

    f32x4 acc[4][4] = {};

    const int e0 = tid * 8;
    const int r0 = e0 >> 5, c0 = (((e0 >> 3) & 3) ^ ((r0 >> 1) & 3)) << 3;
    const int e1 = 2048 + tid * 8;
    const int r1 = e1 >> 5, c1 = (((e1 >> 3) & 3) ^ ((r1 >> 1) & 3)) << 3;

    const bf16_t* Ag0 = A + (size_t)(mBase + r0) * lda + kOff + c0;
    const bf16_t* Ag1 = A + (size_t)(mBase + r1) * lda + kOff + c1;
    const bf16_t* Bg0 = Bt + (size_t)(nBase + r0) * ldb + kOff + c0;
    const bf16_t* Bg1 = Bt + (size_t)(nBase + r1) * ldb + kOff + c1;

    auto stage = [&](int buf, int kb) {
        gld_lds16(Ag0 + kb, As[buf] + e0);
        gld_lds16(Ag1 + kb, As[buf] + e1);
        gld_lds16(Bg0 + kb, Bs[buf] + e0);
        gld_lds16(Bg1 + kb, Bs[buf] + e1);
    };

    stage(0, 0);
    if (32 < K) stage(1, 32);

    int cur = 0;
    for (int kb = 0; kb < K; kb += 32) {
        if (kb + 32 < K) asm volatile("s_waitcnt vmcnt(4)" ::: "memory");
        else             asm volatile("s_waitcnt vmcnt(0)" ::: "memory");
        __builtin_amdgcn_s_barrier();       // buf cur staged for all waves

        bf16x8 af[4], bfr[4];
        #pragma unroll
        for (int mi = 0; mi < 4; mi++) {
            const int R = waveM + mi * 16 + lr;
            af[mi] = *(const bf16x8*)(As[cur] + R * 32 + ((lq ^ ((R >> 1) & 3)) << 3));
        }
        #pragma unroll
        for (int ni = 0; ni < 4; ni++) {
            const int R = waveN + ni * 16 + lr;
            bfr[ni] = *(const bf16x8*)(Bs[cur] + R * 32 + ((lq ^ ((R >> 1) & 3)) << 3));
        }
        #pragma unroll
        for (int mi = 0; mi < 4; mi++)
            #pragma unroll
            for (int ni = 0; ni < 4; ni++)
                acc[mi][ni] = __builtin_amdgcn_mfma_f32_16x16x32_bf16(
                    af[mi], bfr[ni], acc[mi][ni], 0, 0, 0);

        __builtin_amdgcn_s_barrier();       // all waves done reading buf cur
        if (kb + 64 < K) stage(cur, kb + 64);
        cur ^= 1;
    }

    // Epilogue. C/D layout: col(n)=lane&15, row(m)=(lane>>4)*4+reg.
    float sq[4][4];                          // MODE 0 only: per-(mi,r) sum v^2
    if (MODE == 0) {
        #pragma unroll
        for (int a = 0; a < 4; a++)
            #pragma unroll
            for (int b = 0; b < 4; b++) sq[a][b] = 0.0f;
    }
    #pragma unroll
    for (int ni = 0; ni < 4; ni++) {
        const int n = nBase + waveN + ni * 16 + lr;
        const float bz = (MODE == 1 || MODE == 2) ? bias[n] : 0.0f;
        #pragma unroll
        for (int mi = 0; mi < 4; mi++) {
            #pragma unroll
            for (int r = 0; r < 4; r++) {
                const int m = mBase + waveM + mi * 16 + lq * 4 + r;
                float v = acc[mi][ni][r];
                if (MODE == 0) {
                    v = hs_f(v + pmat[(size_t)(m >> 6) * N + n]) * (float)extra[(size_t)m * N + n];
                    const OT vs = (OT)v;
                    Cmat[(size_t)m * N + n] = vs;
                    const float vb = (float)vs;      // bf16-rounded, matches old pass
                    sq[mi][r] += vb * vb;
                } else if (MODE == 1) {
                    v = fmaxf(rowscale[m] * v + bz, 0.0f);
                    Cmat[(size_t)m * N + n] = (OT)v;
                } else if (MODE == 2) {
                    v = v + bz + (float)extra[(size_t)m * N + n];
                    Cmat[(size_t)m * N + n] = (OT)v;
                } else {
                    atomicAdd((float*)&Cmat[(size_t)m * N + n], v);
                }
            }
        }
    }
    if (MODE == 0) {
        // Reduce over the 16-lane column group (lr); lanes lr==0 own the row.
        #pragma unroll
        for (int mi = 0; mi < 4; mi++) {
            #pragma unroll
            for (int r = 0; r < 4; r++) {
                float s = sq[mi][r];
                s += __shfl_xor(s, 1, 64);
                s += __shfl_xor(s, 2, 64);
                s += __shfl_xor(s, 4, 64);
                s += __shfl_xor(s, 8, 64);
                if (lr == 0) {
                    const int m = mBase + waveM + mi * 16 + lq * 4 + r;
                    atomicAdd(&aux[m], s);
                }
            }
        }
    }
}

// ---------------------------------------------------------------------------
extern "C" void kernel_launch(void* const* d_in, const int* in_sizes, int n_in,
                              void* d_out, int out_size, void* d_ws, size_t ws_size,
                              hipStream_t stream) {
    const float* x   = (const float*)d_in[0];
    const float* n1w = (const float*)d_in[1];
    const float* w1  = (const float*)d_in[2];
    const float* b1  = (const float*)d_in[3];
    const float* n2w = (const float*)d_in[4];
    const float* w2a = (const float*)d_in[5];
    const float* b2a = (const float*)d_in[6];
    const float* w2b = (const float*)d_in[7];
    const float* b2b = (const float*)d_in[8];
    float* y = (float*)d_out;

    char* w = (char*)d_ws;
    float*  inv1  = (float*)(w + 0);
    float*  inv2  = (float*)(w + 65536);
    float*  csum  = (float*)(w + 131072);    // also rs2 after scan (64KB head)
    bf16_t* hilo  = (bf16_t*)(w + 1179648);
    float*  Pmat  = (float*)(w + 2228224);
    bf16_t* W1cat = (bf16_t*)(w + 5373952);
    bf16_t* W2at  = (bf16_t*)(w + 9568256);
    bf16_t* W2bt  = (bf16_t*)(w + 17956864);
    bf16_t* outb  = (bf16_t*)(w + 26345472);
    bf16_t* state = (bf16_t*)(w + 59899904);
    bf16_t* hbuf  = state;
    float*  rs2   = csum;                    // csum dead after scan_offsets_hilo

    rms_rows_f32<<<dim3(BT_ / 4), dim3(256), 0, stream>>>(x, inv1);
    scan_emit_local<<<dim3(B_ * NCH_, C_ / 256), dim3(256), 0, stream>>>(x, inv1, n1w, state, csum);
    scan_offsets_hilo<<<dim3(B_ * C_ / 256), dim3(256), 0, stream>>>(csum, hilo);
    transpose_all<<<dim3(9216), dim3(256), 0, stream>>>(
        w1, w2a, w2b, n2w, W1cat, W2at, W2bt);
    pmat_init<<<dim3(256 * C_ / 256), dim3(256), 0, stream>>>(b1, Pmat, rs2);
    gemm_bt<4, float, float><<<dim3(2, C_ / 128, 4), dim3(256), 0, stream>>>(
        hilo, W1cat, nullptr, nullptr, nullptr, nullptr, nullptr, Pmat, C_, 512, 2048, 2048);
    // GEMM1: M=16384, N=1024, K=1024 -> 128x8 = 1024 blocks (+fused rms sumsq)
    gemm_bt<0, float, bf16_t><<<dim3(BT_ / 128, C_ / 128), dim3(256), 0, stream>>>(
        state, W1cat, nullptr, x, nullptr, Pmat, rs2, outb, C_, C_, C_, 2048);
    inv_finish<<<dim3(BT_ / 256), dim3(256), 0, stream>>>(rs2, inv2);
    for (int c = 0; c < BT_ / MCHUNK; c++) {
        const bf16_t* Ao = outb + (size_t)c * MCHUNK * C_;
        float* yo = y + (size_t)c * MCHUNK * C_;
        // GEMM2a: M=8192, N=4096, K=1024 -> 64x32 = 2048 blocks
        gemm_bt<1, float, bf16_t><<<dim3(MCHUNK / 128, H_ / 128), dim3(256), 0, stream>>>(
            Ao, W2at, b2a, nullptr, inv2 + c * MCHUNK, nullptr, nullptr, hbuf, H_, C_, C_, C_);
        // GEMM2b: M=8192, N=1024, K=4096 -> 64x8 = 512 blocks
        gemm_bt<2, bf16_t, float><<<dim3(MCHUNK / 128, C_ / 128), dim3(256), 0, stream>>>(
            hbuf, W2bt, b2b, Ao, nullptr, nullptr, nullptr, yo, C_, H_, H_, H_);
    }
}